// Round 7
// baseline (2494.868 us; speedup 1.0000x reference)
//
#include <hip/hip_runtime.h>
#include <hip/hip_fp16.h>

// GCN: out = dinv ⊙ ( A_sum ( dinv ⊙ (x@W) ) ) + b, A_sum includes self-loop.
// CSR-by-dst-bucket built on-device (bucketed multi-split, LDS atomics).
// Aggregation: one block per (bucket of 128 dst nodes, 32-col slice); edges of the
// bucket are edge-parallel across lanes; each lane gathers its src row's 64B slice
// (4 indep 16B loads -> latency hidden) and scatters into a [128][33] fp32 LDS
// accumulator via ds_add_f32. slice = blockIdx.x & 3 pins each 3.2MB operand slice
// to 2 XCDs' L2s under round-robin dispatch (traffic floor ~26MB).

#define NBUK_MAX 512  // buckets of 128 nodes; N=50000 -> 391 buckets

__global__ __launch_bounds__(256) void k_bhist(const int* __restrict__ dst, int E, int nbuk,
                                               int* __restrict__ bcount) {
    __shared__ int h[NBUK_MAX];
    int tid = threadIdx.x;
    for (int i = tid; i < nbuk; i += 256) h[i] = 0;
    __syncthreads();
    int s0 = blockIdx.x * 4096;
#pragma unroll
    for (int i = 0; i < 16; i++) {
        int e = s0 + i * 256 + tid;
        if (e < E) atomicAdd(&h[dst[e] >> 7], 1);
    }
    __syncthreads();
    for (int i = tid; i < nbuk; i += 256)
        if (h[i]) atomicAdd(&bcount[i], h[i]);
}

__global__ __launch_bounds__(512) void k_bscan(const int* __restrict__ bcount, int nb,
                                               int* __restrict__ bbase, int* __restrict__ bcur) {
    __shared__ int s[512];
    int tid = threadIdx.x;
    int v = (tid < nb) ? bcount[tid] : 0;
    s[tid] = v;
    __syncthreads();
    for (int off = 1; off < 512; off <<= 1) {
        int t = (tid >= off) ? s[tid - off] : 0;
        __syncthreads();
        s[tid] += t;
        __syncthreads();
    }
    if (tid < nb) {
        int excl = s[tid] - v;
        bbase[tid] = excl;
        bcur[tid] = excl;
        if (tid == nb - 1) bbase[nb] = s[tid];
    }
}

__global__ __launch_bounds__(256) void k_passA(const int* __restrict__ src,
                                               const int* __restrict__ dst, int E, int nbuk,
                                               int* __restrict__ bcur,
                                               unsigned* __restrict__ bbuf) {
    __shared__ int h[NBUK_MAX];
    __shared__ int base[NBUK_MAX];
    __shared__ int lcur[NBUK_MAX];
    int tid = threadIdx.x;
    for (int i = tid; i < nbuk; i += 256) h[i] = 0;
    __syncthreads();
    int s0 = blockIdx.x * 4096;
#pragma unroll
    for (int i = 0; i < 16; i++) {
        int e = s0 + i * 256 + tid;
        if (e < E) atomicAdd(&h[dst[e] >> 7], 1);
    }
    __syncthreads();
    for (int i = tid; i < nbuk; i += 256) {
        int c = h[i];
        base[i] = c ? atomicAdd(&bcur[i], c) : 0;
        lcur[i] = 0;
    }
    __syncthreads();
#pragma unroll
    for (int i = 0; i < 16; i++) {
        int e = s0 + i * 256 + tid;
        if (e < E) {
            int d = dst[e];
            int b = d >> 7;
            int idx = atomicAdd(&lcur[b], 1);
            bbuf[base[b] + idx] = ((unsigned)d << 16) | (unsigned)src[e];
        }
    }
}

__global__ __launch_bounds__(256) void k_passB(const unsigned* __restrict__ bbuf,
                                               const int* __restrict__ bbase, int N,
                                               int* __restrict__ row_ptr,
                                               float* __restrict__ dinv,
                                               unsigned short* __restrict__ sorted) {
    __shared__ int h[128], sc[128], lc[128];
    int b = blockIdx.x, tid = threadIdx.x;
    int node0 = b << 7;
    int ncnt = min(128, N - node0);
    int s = bbase[b], e = bbase[b + 1];
    if (tid < 128) h[tid] = 0;
    __syncthreads();
    for (int i = s + tid; i < e; i += 256) atomicAdd(&h[(bbuf[i] >> 16) & 127], 1);
    __syncthreads();
    if (tid < 128) sc[tid] = h[tid];
    __syncthreads();
    for (int off = 1; off < 128; off <<= 1) {
        int t = 0;
        if (tid < 128 && tid >= off) t = sc[tid - off];
        __syncthreads();
        if (tid < 128) sc[tid] += t;
        __syncthreads();
    }
    if (tid < ncnt) {
        int excl = sc[tid] - h[tid];
        row_ptr[node0 + tid] = s + excl;
        dinv[node0 + tid] = rsqrtf((float)(h[tid] + 1));  // +1 self-loop
        lc[tid] = excl;
    }
    if (b == gridDim.x - 1 && tid == 0) row_ptr[N] = e;
    __syncthreads();
    for (int i = s + tid; i < e; i += 256) {
        unsigned p = bbuf[i];
        int nl = (p >> 16) & 127;
        int idx = atomicAdd(&lc[nl], 1);
        sorted[s + idx] = (unsigned short)(p & 0xffffu);
    }
}

// hs[(c>>5)][n][c&31] = (half) dinv[n] * sum_k in[n][k]*W[k][c]  (slice-major [4][N][32])
__global__ __launch_bounds__(256) void k_gemm_scale_h(const float* __restrict__ in,
                                                      const float* __restrict__ W,
                                                      const float* __restrict__ dinv, int N,
                                                      __half* __restrict__ out) {
    __shared__ float Ws[32][128];
    __shared__ float Xs[32][64];
    int tid = threadIdx.x;
    int row0 = blockIdx.x * 64;
    int tc = tid & 15;   // 16 col groups x 8 cols
    int tr = tid >> 4;   // 16 row groups x 4 rows
    float acc[4][8];
#pragma unroll
    for (int i = 0; i < 4; i++)
#pragma unroll
        for (int j = 0; j < 8; j++) acc[i][j] = 0.f;

    for (int k0 = 0; k0 < 128; k0 += 32) {
#pragma unroll
        for (int j = 0; j < 4; j++) {  // stage W chunk: 32x128 = 1024 float4
            int u = tid + j * 256;
            int kk = u >> 5, c4 = u & 31;
            *(float4*)&Ws[kk][c4 * 4] = *(const float4*)&W[(k0 + kk) * 128 + c4 * 4];
        }
#pragma unroll
        for (int j = 0; j < 2; j++) {  // stage X chunk transposed: 64 rows x 32 k
            int u = tid + j * 256;     // 512 float4 units
            int r = u >> 3, kq = u & 7;
            int row = row0 + r;
            if (row > N - 1) row = N - 1;
            float4 v = *(const float4*)&in[(size_t)row * 128 + k0 + kq * 4];
            Xs[kq * 4 + 0][r] = v.x;
            Xs[kq * 4 + 1][r] = v.y;
            Xs[kq * 4 + 2][r] = v.z;
            Xs[kq * 4 + 3][r] = v.w;
        }
        __syncthreads();
#pragma unroll 8
        for (int kk = 0; kk < 32; kk++) {
            float4 xv = *(const float4*)&Xs[kk][tr * 4];
            float4 wa = *(const float4*)&Ws[kk][tc * 8];
            float4 wb = *(const float4*)&Ws[kk][tc * 8 + 4];
            float xr[4] = {xv.x, xv.y, xv.z, xv.w};
            float wc[8] = {wa.x, wa.y, wa.z, wa.w, wb.x, wb.y, wb.z, wb.w};
#pragma unroll
            for (int i = 0; i < 4; i++)
#pragma unroll
                for (int j = 0; j < 8; j++) acc[i][j] += xr[i] * wc[j];
        }
        __syncthreads();
    }
#pragma unroll
    for (int i = 0; i < 4; i++) {
        int row = row0 + tr * 4 + i;
        if (row < N) {
            float di = dinv[row];
            union {
                uint4 u;
                __half h[8];
            } pk;
#pragma unroll
            for (int j = 0; j < 8; j++) pk.h[j] = __float2half_rn(di * acc[i][j]);
            // slice-major [4][N][32]: slice = tc>>2, col-in-slice = (tc&3)*8
            *(uint4*)&out[((size_t)(tc >> 2) * N + row) * 32 + (tc & 3) * 8] = pk.u;
        }
    }
}

// scatter aggregation: block = (bucket bkt, slice sl). LDS acc[128][33] fp32.
// Edge-parallel: lane owns edge, 4 indep 16B gathers, 32 ds_add_f32 scatters.
__global__ __launch_bounds__(256) void k_aggsc(const __half* __restrict__ hs,  // [4][N][32]
                                               const unsigned* __restrict__ bbuf,
                                               const int* __restrict__ bbase,
                                               const float* __restrict__ dinv,
                                               const float* __restrict__ bias, int N,
                                               int do_relu, float* __restrict__ out) {
    __shared__ float acc[128 * 33];
    int sl = blockIdx.x & 3;
    int bkt = blockIdx.x >> 2;
    int tid = threadIdx.x;
    int node0 = bkt << 7;
    int ncnt = min(128, N - node0);
    const __half* hsl = hs + (size_t)sl * N * 32;

    for (int t = tid; t < 128 * 33; t += 256) acc[t] = 0.f;
    __syncthreads();

    int s = bbase[bkt], e = bbase[bkt + 1];
    for (int i = s + tid; i < e; i += 256) {
        unsigned p = bbuf[i];
        int dl = (p >> 16) & 127;
        int srcn = p & 0xffff;
        const uint4* rp = (const uint4*)(hsl + (size_t)srcn * 32);
        uint4 q0 = rp[0], q1 = rp[1], q2 = rp[2], q3 = rp[3];
        float* arow = &acc[dl * 33];
        union {
            uint4 q;
            __half h[8];
        } u;
        u.q = q0;
#pragma unroll
        for (int k = 0; k < 8; k++) atomicAdd(&arow[k], __half2float(u.h[k]));
        u.q = q1;
#pragma unroll
        for (int k = 0; k < 8; k++) atomicAdd(&arow[8 + k], __half2float(u.h[k]));
        u.q = q2;
#pragma unroll
        for (int k = 0; k < 8; k++) atomicAdd(&arow[16 + k], __half2float(u.h[k]));
        u.q = q3;
#pragma unroll
        for (int k = 0; k < 8; k++) atomicAdd(&arow[24 + k], __half2float(u.h[k]));
    }
    __syncthreads();

    // epilogue: out[node][sl*32 + c] = relu(dinv*(acc + self) + bias)
    int nl = tid >> 1;
    int ch = (tid & 1) * 16;
    if (nl < ncnt) {
        int node = node0 + nl;
        float di = dinv[node];
        const __half* srow = hsl + (size_t)node * 32 + ch;
        float* arow = &acc[nl * 33 + ch];
        const float* bp = &bias[sl * 32 + ch];
        float* op = &out[(size_t)node * 128 + sl * 32 + ch];
#pragma unroll
        for (int j = 0; j < 4; j++) {
            float4 o;
            float vv[4];
#pragma unroll
            for (int k = 0; k < 4; k++) {
                float a = arow[j * 4 + k] + __half2float(srow[j * 4 + k]);
                float v = di * a + bp[j * 4 + k];
                if (do_relu) v = fmaxf(v, 0.f);
                vv[k] = v;
            }
            o.x = vv[0];
            o.y = vv[1];
            o.z = vv[2];
            o.w = vv[3];
            *(float4*)&op[j * 4] = o;
        }
    }
}

// heads: ths[n][j] = dinv[n] * sum_k h[n][k] * Wcat[k][j], Wcat = [W_age|W_sex|W_eth]
__global__ __launch_bounds__(256) void k_headgemm(const float* __restrict__ h,
                                                  const float* __restrict__ Wa,
                                                  const float* __restrict__ Wsx,
                                                  const float* __restrict__ We,
                                                  const float* __restrict__ dinv, int N,
                                                  float* __restrict__ ths) {
    __shared__ float Ws8[128][8];
    int tid = threadIdx.x;
#pragma unroll
    for (int j = 0; j < 4; j++) {
        int u = tid + j * 256;  // 1024 entries
        int k = u >> 3, c = u & 7;
        float v;
        if (c < 3) v = Wa[k * 3 + c];
        else if (c < 5) v = Wsx[k * 2 + (c - 3)];
        else v = We[k * 3 + (c - 5)];
        Ws8[k][c] = v;
    }
    __syncthreads();
    int node = blockIdx.x * 32 + (tid >> 3);
    int col = tid & 7;
    if (node >= N) return;
    const float* hr = &h[(size_t)node * 128];
    float acc = 0.f;
#pragma unroll 4
    for (int k = 0; k < 128; k += 4) {
        float4 hv = *(const float4*)&hr[k];
        acc += hv.x * Ws8[k][col] + hv.y * Ws8[k + 1][col] + hv.z * Ws8[k + 2][col] +
               hv.w * Ws8[k + 3][col];
    }
    ths[(size_t)node * 8 + col] = dinv[node] * acc;
}

__global__ __launch_bounds__(256) void k_agg8(const float* __restrict__ ths,
                                              const int* __restrict__ row_ptr,
                                              const unsigned short* __restrict__ ss,
                                              const float* __restrict__ dinv,
                                              const float* __restrict__ ba,
                                              const float* __restrict__ bs,
                                              const float* __restrict__ be, int N,
                                              float* __restrict__ outp) {
    int tid = threadIdx.x;
    int node = blockIdx.x * 32 + (tid >> 3);
    int j = tid & 7;
    if (node >= N) return;
    float acc = ths[(size_t)node * 8 + j];  // self
    int s = row_ptr[node], e = row_ptr[node + 1];
    for (int i = s; i < e; i++) {
        int sc = ss[i];
        acc += ths[(size_t)sc * 8 + j];
    }
    float bias = (j < 3) ? ba[j] : ((j < 5) ? bs[j - 3] : be[j - 5]);
    float v = dinv[node] * acc + bias;
    if (j < 3) outp[(size_t)node * 3 + j] = v;
    else if (j < 5) outp[(size_t)N * 3 + (size_t)node * 2 + (j - 3)] = v;
    else outp[(size_t)N * 5 + (size_t)node * 3 + (j - 5)] = v;
}

extern "C" void kernel_launch(void* const* d_in, const int* in_sizes, int n_in,
                              void* d_out, int out_size, void* d_ws, size_t ws_size,
                              hipStream_t stream) {
    const float* x = (const float*)d_in[0];
    const int* edge = (const int*)d_in[1];
    const float* W1 = (const float*)d_in[2];
    const float* b1 = (const float*)d_in[3];
    const float* W2 = (const float*)d_in[4];
    const float* b2 = (const float*)d_in[5];
    const float* Wa = (const float*)d_in[6];
    const float* ba = (const float*)d_in[7];
    const float* Wsx = (const float*)d_in[8];
    const float* bs = (const float*)d_in[9];
    const float* We = (const float*)d_in[10];
    const float* be = (const float*)d_in[11];

    int N = in_sizes[0] / 128;
    int E = in_sizes[1] / 2;
    const int* srcp = edge;
    const int* dstp = edge + E;
    int nbuk = (N + 127) >> 7;

    char* ws = (char*)d_ws;
    size_t off = 0;
    auto alloc = [&](size_t bytes) -> char* {
        char* p = ws + off;
        off += (bytes + 255) & ~(size_t)255;
        return p;
    };
    int* bcount = (int*)alloc((size_t)(nbuk + 1) * 4);
    int* bbase = (int*)alloc((size_t)(nbuk + 1) * 4);
    int* bcur = (int*)alloc((size_t)(nbuk + 1) * 4);
    int* row_ptr = (int*)alloc((size_t)(N + 1) * 4);
    float* dinv = (float*)alloc((size_t)N * 4);
    unsigned* bbuf = (unsigned*)alloc((size_t)E * 4);
    unsigned short* sorted = (unsigned short*)alloc((size_t)E * 2);
    __half* bufH = (__half*)alloc((size_t)N * 128 * 2);  // slice-major [4][N][32] fp16
    float* bufF = (float*)alloc((size_t)N * 128 * 4);    // fp32 agg output / gemm input
    float* ths = (float*)alloc((size_t)N * 8 * 4);

    int nbT = (E + 4095) / 4096;

    hipMemsetAsync(bcount, 0, (size_t)(nbuk + 1) * 4, stream);
    k_bhist<<<nbT, 256, 0, stream>>>(dstp, E, nbuk, bcount);
    k_bscan<<<1, 512, 0, stream>>>(bcount, nbuk, bbase, bcur);
    k_passA<<<nbT, 256, 0, stream>>>(srcp, dstp, E, nbuk, bcur, bbuf);
    k_passB<<<nbuk, 256, 0, stream>>>(bbuf, bbase, N, row_ptr, dinv, sorted);

    int gb = (N + 63) / 64;
    int agrid = nbuk * 4;
    k_gemm_scale_h<<<gb, 256, 0, stream>>>(x, W1, dinv, N, bufH);
    k_aggsc<<<agrid, 256, 0, stream>>>(bufH, bbuf, bbase, dinv, b1, N, 1, bufF);
    k_gemm_scale_h<<<gb, 256, 0, stream>>>(bufF, W2, dinv, N, bufH);
    k_aggsc<<<agrid, 256, 0, stream>>>(bufH, bbuf, bbase, dinv, b2, N, 1, bufF);
    k_headgemm<<<(N + 31) / 32, 256, 0, stream>>>(bufF, Wa, Wsx, We, dinv, N, ths);
    k_agg8<<<(N + 31) / 32, 256, 0, stream>>>(ths, row_ptr, sorted, dinv, ba, bs, be, N,
                                              (float*)d_out);
}

// Round 8
// 295.183 us; speedup vs baseline: 8.4519x; 8.4519x over previous
//
#include <hip/hip_runtime.h>
#include <hip/hip_fp16.h>

// GCN: out = dinv ⊙ ( A_sum ( dinv ⊙ (x@W) ) ) + b, A_sum includes self-loop.
// CSR (by dst) built on-device via bucketed multi-split (LDS atomics on hot path).
// Aggregation: fp16 gather operand slice-major [2][N][64]; slice = blockIdx.x & 1
// pins each 6.4MB slice to 4 XCDs (halves per-XCD L2 footprint vs row-major).
// Wave per (node, slice): 2 edge-groups x 32 colpair lanes, 8-deep unrolled gather
// (8 loads in flight), shfl_xor(32) reduce, fp32 accumulate.

#define NBUK_MAX 512  // buckets of 128 nodes; N=50000 -> 391 buckets

__global__ __launch_bounds__(256) void k_bhist(const int* __restrict__ dst, int E, int nbuk,
                                               int* __restrict__ bcount) {
    __shared__ int h[NBUK_MAX];
    int tid = threadIdx.x;
    for (int i = tid; i < nbuk; i += 256) h[i] = 0;
    __syncthreads();
    int s0 = blockIdx.x * 4096;
#pragma unroll
    for (int i = 0; i < 16; i++) {
        int e = s0 + i * 256 + tid;
        if (e < E) atomicAdd(&h[dst[e] >> 7], 1);
    }
    __syncthreads();
    for (int i = tid; i < nbuk; i += 256)
        if (h[i]) atomicAdd(&bcount[i], h[i]);
}

__global__ __launch_bounds__(512) void k_bscan(const int* __restrict__ bcount, int nb,
                                               int* __restrict__ bbase, int* __restrict__ bcur) {
    __shared__ int s[512];
    int tid = threadIdx.x;
    int v = (tid < nb) ? bcount[tid] : 0;
    s[tid] = v;
    __syncthreads();
    for (int off = 1; off < 512; off <<= 1) {
        int t = (tid >= off) ? s[tid - off] : 0;
        __syncthreads();
        s[tid] += t;
        __syncthreads();
    }
    if (tid < nb) {
        int excl = s[tid] - v;
        bbase[tid] = excl;
        bcur[tid] = excl;
        if (tid == nb - 1) bbase[nb] = s[tid];
    }
}

__global__ __launch_bounds__(256) void k_passA(const int* __restrict__ src,
                                               const int* __restrict__ dst, int E, int nbuk,
                                               int* __restrict__ bcur,
                                               unsigned* __restrict__ bbuf) {
    __shared__ int h[NBUK_MAX];
    __shared__ int base[NBUK_MAX];
    __shared__ int lcur[NBUK_MAX];
    int tid = threadIdx.x;
    for (int i = tid; i < nbuk; i += 256) h[i] = 0;
    __syncthreads();
    int s0 = blockIdx.x * 4096;
#pragma unroll
    for (int i = 0; i < 16; i++) {
        int e = s0 + i * 256 + tid;
        if (e < E) atomicAdd(&h[dst[e] >> 7], 1);
    }
    __syncthreads();
    for (int i = tid; i < nbuk; i += 256) {
        int c = h[i];
        base[i] = c ? atomicAdd(&bcur[i], c) : 0;
        lcur[i] = 0;
    }
    __syncthreads();
#pragma unroll
    for (int i = 0; i < 16; i++) {
        int e = s0 + i * 256 + tid;
        if (e < E) {
            int d = dst[e];
            int b = d >> 7;
            int idx = atomicAdd(&lcur[b], 1);
            bbuf[base[b] + idx] = ((unsigned)d << 16) | (unsigned)src[e];
        }
    }
}

__global__ __launch_bounds__(256) void k_passB(const unsigned* __restrict__ bbuf,
                                               const int* __restrict__ bbase, int N,
                                               int* __restrict__ row_ptr,
                                               float* __restrict__ dinv,
                                               unsigned short* __restrict__ sorted) {
    __shared__ int h[128], sc[128], lc[128];
    int b = blockIdx.x, tid = threadIdx.x;
    int node0 = b << 7;
    int ncnt = min(128, N - node0);
    int s = bbase[b], e = bbase[b + 1];
    if (tid < 128) h[tid] = 0;
    __syncthreads();
    for (int i = s + tid; i < e; i += 256) atomicAdd(&h[(bbuf[i] >> 16) & 127], 1);
    __syncthreads();
    if (tid < 128) sc[tid] = h[tid];
    __syncthreads();
    for (int off = 1; off < 128; off <<= 1) {
        int t = 0;
        if (tid < 128 && tid >= off) t = sc[tid - off];
        __syncthreads();
        if (tid < 128) sc[tid] += t;
        __syncthreads();
    }
    if (tid < ncnt) {
        int excl = sc[tid] - h[tid];
        row_ptr[node0 + tid] = s + excl;
        dinv[node0 + tid] = rsqrtf((float)(h[tid] + 1));  // +1 self-loop
        lc[tid] = excl;
    }
    if (b == gridDim.x - 1 && tid == 0) row_ptr[N] = e;
    __syncthreads();
    for (int i = s + tid; i < e; i += 256) {
        unsigned p = bbuf[i];
        int nl = (p >> 16) & 127;
        int idx = atomicAdd(&lc[nl], 1);
        sorted[s + idx] = (unsigned short)(p & 0xffffu);
    }
}

// hs[(c>>6)][n][c&63] = (half) dinv[n] * sum_k in[n][k]*W[k][c]  (slice-major [2][N][64])
__global__ __launch_bounds__(256) void k_gemm_scale_h(const float* __restrict__ in,
                                                      const float* __restrict__ W,
                                                      const float* __restrict__ dinv, int N,
                                                      __half* __restrict__ out) {
    __shared__ float Ws[32][128];
    __shared__ float Xs[32][64];
    int tid = threadIdx.x;
    int row0 = blockIdx.x * 64;
    int tc = tid & 15;   // 16 col groups x 8 cols
    int tr = tid >> 4;   // 16 row groups x 4 rows
    float acc[4][8];
#pragma unroll
    for (int i = 0; i < 4; i++)
#pragma unroll
        for (int j = 0; j < 8; j++) acc[i][j] = 0.f;

    for (int k0 = 0; k0 < 128; k0 += 32) {
#pragma unroll
        for (int j = 0; j < 4; j++) {  // stage W chunk: 32x128 = 1024 float4
            int u = tid + j * 256;
            int kk = u >> 5, c4 = u & 31;
            *(float4*)&Ws[kk][c4 * 4] = *(const float4*)&W[(k0 + kk) * 128 + c4 * 4];
        }
#pragma unroll
        for (int j = 0; j < 2; j++) {  // stage X chunk transposed: 64 rows x 32 k
            int u = tid + j * 256;     // 512 float4 units
            int r = u >> 3, kq = u & 7;
            int row = row0 + r;
            if (row > N - 1) row = N - 1;
            float4 v = *(const float4*)&in[(size_t)row * 128 + k0 + kq * 4];
            Xs[kq * 4 + 0][r] = v.x;
            Xs[kq * 4 + 1][r] = v.y;
            Xs[kq * 4 + 2][r] = v.z;
            Xs[kq * 4 + 3][r] = v.w;
        }
        __syncthreads();
#pragma unroll 8
        for (int kk = 0; kk < 32; kk++) {
            float4 xv = *(const float4*)&Xs[kk][tr * 4];
            float4 wa = *(const float4*)&Ws[kk][tc * 8];
            float4 wb = *(const float4*)&Ws[kk][tc * 8 + 4];
            float xr[4] = {xv.x, xv.y, xv.z, xv.w};
            float wc[8] = {wa.x, wa.y, wa.z, wa.w, wb.x, wb.y, wb.z, wb.w};
#pragma unroll
            for (int i = 0; i < 4; i++)
#pragma unroll
                for (int j = 0; j < 8; j++) acc[i][j] += xr[i] * wc[j];
        }
        __syncthreads();
    }
#pragma unroll
    for (int i = 0; i < 4; i++) {
        int row = row0 + tr * 4 + i;
        if (row < N) {
            float di = dinv[row];
            union {
                uint4 u;
                __half h[8];
            } pk;
#pragma unroll
            for (int j = 0; j < 8; j++) pk.h[j] = __float2half_rn(di * acc[i][j]);
            // slice-major [2][N][64]: slice = tc>>3, col-in-slice = (tc&7)*8
            *(uint4*)&out[((size_t)(tc >> 3) * N + row) * 64 + (tc & 7) * 8] = pk.u;
        }
    }
}

// slice-partitioned pull aggregation: slice = blockIdx.x & 1 (pins 6.4MB slice to
// 4 XCDs). Wave per (node, slice): g = lane>>5 edge-group, c = lane&31 colpair;
// 8-deep unrolled gather; shfl_xor(32) reduce; fp32 accumulate.
__global__ __launch_bounds__(256) void k_agg64s(const __half* __restrict__ hs,
                                                const int* __restrict__ row_ptr,
                                                const unsigned short* __restrict__ ss,
                                                const float* __restrict__ dinv,
                                                const float* __restrict__ bias, int N,
                                                int do_relu, float* __restrict__ out) {
    int slice = blockIdx.x & 1;
    int nb = blockIdx.x >> 1;
    int wid = threadIdx.x >> 6;
    int lane = threadIdx.x & 63;
    int node = nb * 4 + wid;
    if (node >= N) return;
    int g = lane >> 5;   // edge subgroup 0..1
    int c = lane & 31;   // colpair 0..31 (64 cols per slice)
    const __half2* hp = (const __half2*)(hs + (size_t)slice * N * 64);  // row stride 32
    float2 acc = {0.f, 0.f};
    int s = row_ptr[node], e = row_ptr[node + 1];
    int i = s + g;
    for (; i + 14 < e; i += 16) {  // 8 edges per group per trip, 8 loads in flight
        int id[8];
#pragma unroll
        for (int u = 0; u < 8; u++) id[u] = ss[i + u * 2];
        float2 v[8];
#pragma unroll
        for (int u = 0; u < 8; u++) v[u] = __half22float2(hp[(size_t)id[u] * 32 + c]);
        float sx0 = (v[0].x + v[1].x) + (v[2].x + v[3].x);
        float sx1 = (v[4].x + v[5].x) + (v[6].x + v[7].x);
        float sy0 = (v[0].y + v[1].y) + (v[2].y + v[3].y);
        float sy1 = (v[4].y + v[5].y) + (v[6].y + v[7].y);
        acc.x += sx0 + sx1;
        acc.y += sy0 + sy1;
    }
    for (; i < e; i += 2) {
        float2 v0 = __half22float2(hp[(size_t)ss[i] * 32 + c]);
        acc.x += v0.x;
        acc.y += v0.y;
    }
    acc.x += __shfl_xor(acc.x, 32);
    acc.y += __shfl_xor(acc.y, 32);
    if (g == 0) {
        float2 sv = __half22float2(hp[(size_t)node * 32 + c]);  // self-loop term
        acc.x += sv.x;
        acc.y += sv.y;
        float di = dinv[node];
        float2 b = *(const float2*)&bias[slice * 64 + c * 2];
        float ox = di * acc.x + b.x;
        float oy = di * acc.y + b.y;
        if (do_relu) {
            ox = fmaxf(ox, 0.f);
            oy = fmaxf(oy, 0.f);
        }
        *(float2*)&out[(size_t)node * 128 + slice * 64 + c * 2] = {ox, oy};
    }
}

// heads: ths[n][j] = dinv[n] * sum_k h[n][k] * Wcat[k][j], Wcat = [W_age|W_sex|W_eth]
__global__ __launch_bounds__(256) void k_headgemm(const float* __restrict__ h,
                                                  const float* __restrict__ Wa,
                                                  const float* __restrict__ Wsx,
                                                  const float* __restrict__ We,
                                                  const float* __restrict__ dinv, int N,
                                                  float* __restrict__ ths) {
    __shared__ float Ws8[128][8];
    int tid = threadIdx.x;
#pragma unroll
    for (int j = 0; j < 4; j++) {
        int u = tid + j * 256;  // 1024 entries
        int k = u >> 3, c = u & 7;
        float v;
        if (c < 3) v = Wa[k * 3 + c];
        else if (c < 5) v = Wsx[k * 2 + (c - 3)];
        else v = We[k * 3 + (c - 5)];
        Ws8[k][c] = v;
    }
    __syncthreads();
    int node = blockIdx.x * 32 + (tid >> 3);
    int col = tid & 7;
    if (node >= N) return;
    const float* hr = &h[(size_t)node * 128];
    float acc = 0.f;
#pragma unroll 4
    for (int k = 0; k < 128; k += 4) {
        float4 hv = *(const float4*)&hr[k];
        acc += hv.x * Ws8[k][col] + hv.y * Ws8[k + 1][col] + hv.z * Ws8[k + 2][col] +
               hv.w * Ws8[k + 3][col];
    }
    ths[(size_t)node * 8 + col] = dinv[node] * acc;
}

__global__ __launch_bounds__(256) void k_agg8(const float* __restrict__ ths,
                                              const int* __restrict__ row_ptr,
                                              const unsigned short* __restrict__ ss,
                                              const float* __restrict__ dinv,
                                              const float* __restrict__ ba,
                                              const float* __restrict__ bs,
                                              const float* __restrict__ be, int N,
                                              float* __restrict__ outp) {
    int tid = threadIdx.x;
    int node = blockIdx.x * 32 + (tid >> 3);
    int j = tid & 7;
    if (node >= N) return;
    float acc = ths[(size_t)node * 8 + j];  // self
    int s = row_ptr[node], e = row_ptr[node + 1];
    for (int i = s; i < e; i++) {
        int sc = ss[i];
        acc += ths[(size_t)sc * 8 + j];
    }
    float bias = (j < 3) ? ba[j] : ((j < 5) ? bs[j - 3] : be[j - 5]);
    float v = dinv[node] * acc + bias;
    if (j < 3) outp[(size_t)node * 3 + j] = v;
    else if (j < 5) outp[(size_t)N * 3 + (size_t)node * 2 + (j - 3)] = v;
    else outp[(size_t)N * 5 + (size_t)node * 3 + (j - 5)] = v;
}

extern "C" void kernel_launch(void* const* d_in, const int* in_sizes, int n_in,
                              void* d_out, int out_size, void* d_ws, size_t ws_size,
                              hipStream_t stream) {
    const float* x = (const float*)d_in[0];
    const int* edge = (const int*)d_in[1];
    const float* W1 = (const float*)d_in[2];
    const float* b1 = (const float*)d_in[3];
    const float* W2 = (const float*)d_in[4];
    const float* b2 = (const float*)d_in[5];
    const float* Wa = (const float*)d_in[6];
    const float* ba = (const float*)d_in[7];
    const float* Wsx = (const float*)d_in[8];
    const float* bs = (const float*)d_in[9];
    const float* We = (const float*)d_in[10];
    const float* be = (const float*)d_in[11];

    int N = in_sizes[0] / 128;
    int E = in_sizes[1] / 2;
    const int* srcp = edge;
    const int* dstp = edge + E;
    int nbuk = (N + 127) >> 7;

    char* ws = (char*)d_ws;
    size_t off = 0;
    auto alloc = [&](size_t bytes) -> char* {
        char* p = ws + off;
        off += (bytes + 255) & ~(size_t)255;
        return p;
    };
    int* bcount = (int*)alloc((size_t)(nbuk + 1) * 4);
    int* bbase = (int*)alloc((size_t)(nbuk + 1) * 4);
    int* bcur = (int*)alloc((size_t)(nbuk + 1) * 4);
    int* row_ptr = (int*)alloc((size_t)(N + 1) * 4);
    float* dinv = (float*)alloc((size_t)N * 4);
    unsigned* bbuf = (unsigned*)alloc((size_t)E * 4);
    unsigned short* sorted = (unsigned short*)alloc((size_t)E * 2);
    __half* bufH = (__half*)alloc((size_t)N * 128 * 2);  // slice-major [2][N][64] fp16
    float* bufF = (float*)alloc((size_t)N * 128 * 4);    // fp32 agg output / gemm input
    float* ths = (float*)alloc((size_t)N * 8 * 4);

    int nbT = (E + 4095) / 4096;

    hipMemsetAsync(bcount, 0, (size_t)(nbuk + 1) * 4, stream);
    k_bhist<<<nbT, 256, 0, stream>>>(dstp, E, nbuk, bcount);
    k_bscan<<<1, 512, 0, stream>>>(bcount, nbuk, bbase, bcur);
    k_passA<<<nbT, 256, 0, stream>>>(srcp, dstp, E, nbuk, bcur, bbuf);
    k_passB<<<nbuk, 256, 0, stream>>>(bbuf, bbase, N, row_ptr, dinv, sorted);

    int gb = (N + 63) / 64;
    int agrid = 2 * ((N + 3) / 4);
    k_gemm_scale_h<<<gb, 256, 0, stream>>>(x, W1, dinv, N, bufH);
    k_agg64s<<<agrid, 256, 0, stream>>>(bufH, row_ptr, sorted, dinv, b1, N, 1, bufF);
    k_gemm_scale_h<<<gb, 256, 0, stream>>>(bufF, W2, dinv, N, bufH);
    k_agg64s<<<agrid, 256, 0, stream>>>(bufH, row_ptr, sorted, dinv, b2, N, 1, bufF);
    k_headgemm<<<(N + 31) / 32, 256, 0, stream>>>(bufF, Wa, Wsx, We, dinv, N, ths);
    k_agg8<<<(N + 31) / 32, 256, 0, stream>>>(ths, row_ptr, sorted, dinv, ba, bs, be, N,
                                              (float*)d_out);
}

// Round 9
// 294.069 us; speedup vs baseline: 8.4840x; 1.0038x over previous
//
#include <hip/hip_runtime.h>
#include <hip/hip_fp16.h>

// GCN: out = dinv ⊙ ( A_sum ( dinv ⊙ (x@W) ) ) + b, A_sum includes self-loop.
// CSR (by dst) via bucketed multi-split. Pull aggregation (1 wave = 1 node) over
// row-major fp16 hs. GEMM = MFMA 16x16x32_f16 with split-fp16 (Markidis 3-term):
// x = hi+lo fp16, W pre-transposed+split -> ~fp32 accuracy at matrix-core speed.

#define NBUK_MAX 512  // buckets of 128 nodes; N=50000 -> 391 buckets
#define EPB 8192      // edges per block in hist/multisplit

typedef _Float16 f16x8 __attribute__((ext_vector_type(8)));
typedef float f32x4 __attribute__((ext_vector_type(4)));

__global__ __launch_bounds__(256) void k_bhist(const int* __restrict__ dst, int E, int nbuk,
                                               int* __restrict__ bcount) {
    __shared__ int h[NBUK_MAX];
    int tid = threadIdx.x;
    for (int i = tid; i < nbuk; i += 256) h[i] = 0;
    __syncthreads();
    int s0 = blockIdx.x * EPB;
#pragma unroll
    for (int i = 0; i < EPB / 256; i++) {
        int e = s0 + i * 256 + tid;
        if (e < E) atomicAdd(&h[dst[e] >> 7], 1);
    }
    __syncthreads();
    for (int i = tid; i < nbuk; i += 256)
        if (h[i]) atomicAdd(&bcount[i], h[i]);
}

__global__ __launch_bounds__(512) void k_bscan(const int* __restrict__ bcount, int nb,
                                               int* __restrict__ bbase, int* __restrict__ bcur) {
    __shared__ int s[512];
    int tid = threadIdx.x;
    int v = (tid < nb) ? bcount[tid] : 0;
    s[tid] = v;
    __syncthreads();
    for (int off = 1; off < 512; off <<= 1) {
        int t = (tid >= off) ? s[tid - off] : 0;
        __syncthreads();
        s[tid] += t;
        __syncthreads();
    }
    if (tid < nb) {
        int excl = s[tid] - v;
        bbase[tid] = excl;
        bcur[tid] = excl;
        if (tid == nb - 1) bbase[nb] = s[tid];
    }
}

__global__ __launch_bounds__(256) void k_passA(const int* __restrict__ src,
                                               const int* __restrict__ dst, int E, int nbuk,
                                               int* __restrict__ bcur,
                                               unsigned* __restrict__ bbuf) {
    __shared__ int h[NBUK_MAX];
    __shared__ int base[NBUK_MAX];
    __shared__ int lcur[NBUK_MAX];
    int tid = threadIdx.x;
    for (int i = tid; i < nbuk; i += 256) h[i] = 0;
    __syncthreads();
    int s0 = blockIdx.x * EPB;
#pragma unroll
    for (int i = 0; i < EPB / 256; i++) {
        int e = s0 + i * 256 + tid;
        if (e < E) atomicAdd(&h[dst[e] >> 7], 1);
    }
    __syncthreads();
    for (int i = tid; i < nbuk; i += 256) {
        int c = h[i];
        base[i] = c ? atomicAdd(&bcur[i], c) : 0;
        lcur[i] = 0;
    }
    __syncthreads();
#pragma unroll
    for (int i = 0; i < EPB / 256; i++) {
        int e = s0 + i * 256 + tid;
        if (e < E) {
            int d = dst[e];
            int b = d >> 7;
            int idx = atomicAdd(&lcur[b], 1);
            bbuf[base[b] + idx] = ((unsigned)d << 16) | (unsigned)src[e];
        }
    }
}

__global__ __launch_bounds__(256) void k_passB(const unsigned* __restrict__ bbuf,
                                               const int* __restrict__ bbase, int N,
                                               int* __restrict__ row_ptr,
                                               float* __restrict__ dinv,
                                               unsigned short* __restrict__ sorted) {
    __shared__ int h[128], sc[128], lc[128];
    int b = blockIdx.x, tid = threadIdx.x;
    int node0 = b << 7;
    int ncnt = min(128, N - node0);
    int s = bbase[b], e = bbase[b + 1];
    if (tid < 128) h[tid] = 0;
    __syncthreads();
    for (int i = s + tid; i < e; i += 256) atomicAdd(&h[(bbuf[i] >> 16) & 127], 1);
    __syncthreads();
    if (tid < 128) sc[tid] = h[tid];
    __syncthreads();
    for (int off = 1; off < 128; off <<= 1) {
        int t = 0;
        if (tid < 128 && tid >= off) t = sc[tid - off];
        __syncthreads();
        if (tid < 128) sc[tid] += t;
        __syncthreads();
    }
    if (tid < ncnt) {
        int excl = sc[tid] - h[tid];
        row_ptr[node0 + tid] = s + excl;
        dinv[node0 + tid] = rsqrtf((float)(h[tid] + 1));  // +1 self-loop
        lc[tid] = excl;
    }
    if (b == gridDim.x - 1 && tid == 0) row_ptr[N] = e;
    __syncthreads();
    for (int i = s + tid; i < e; i += 256) {
        unsigned p = bbuf[i];
        int nl = (p >> 16) & 127;
        int idx = atomicAdd(&lc[nl], 1);
        sorted[s + idx] = (unsigned short)(p & 0xffffu);
    }
}

// W [128][128] fp32 -> Wt_hi/Wt_lo [c][k] fp16 (transposed + split)
__global__ __launch_bounds__(64) void k_wsplit(const float* __restrict__ W,
                                               __half* __restrict__ wth,
                                               __half* __restrict__ wtl) {
    int t = blockIdx.x * 64 + threadIdx.x;  // 0..2047
#pragma unroll
    for (int u = 0; u < 8; u++) {
        int idx = t * 8 + u;  // 0..16383
        int k = idx >> 7, c = idx & 127;
        float w = W[k * 128 + c];
        _Float16 h = (_Float16)w;
        _Float16 l = (_Float16)(w - (float)h);
        wth[c * 128 + k] = *(__half*)&h;
        wtl[c * 128 + k] = *(__half*)&l;
    }
}

// out[n][c] = (half) dinv[n] * sum_k in[n][k]*W[k][c] via MFMA 16x16x32_f16,
// split-fp16: acc = Ah*Bh + Al*Bh + Ah*Bl (Al*Bl term ~2^-22, dropped).
// Fragments: A/B lane l -> m/n = l&15, k = (l>>4)*8 + j; D lane l -> col = l&15,
// row = (l>>4)*4 + reg.
__global__ __launch_bounds__(256) void k_gemm_mfma(const float* __restrict__ in,
                                                   const __half* __restrict__ wth,
                                                   const __half* __restrict__ wtl,
                                                   const float* __restrict__ dinv, int N,
                                                   __half* __restrict__ out) {
    int wid = threadIdx.x >> 6;
    int lane = threadIdx.x & 63;
    int row0 = blockIdx.x * 64 + wid * 16;
    int lr = lane & 15;        // A row in tile / D col
    int lk = (lane >> 4) * 8;  // k sub-chunk base

    // A fragments (hi/lo) for the 4 K-steps
    f16x8 ah[4], al[4];
    int arow = row0 + lr;
    if (arow > N - 1) arow = N - 1;
    const float* xr = &in[(size_t)arow * 128];
#pragma unroll
    for (int ks = 0; ks < 4; ks++) {
        float4 a0 = *(const float4*)&xr[ks * 32 + lk];
        float4 a1 = *(const float4*)&xr[ks * 32 + lk + 4];
        float av[8] = {a0.x, a0.y, a0.z, a0.w, a1.x, a1.y, a1.z, a1.w};
#pragma unroll
        for (int j = 0; j < 8; j++) {
            _Float16 h = (_Float16)av[j];
            ah[ks][j] = h;
            al[ks][j] = (_Float16)(av[j] - (float)h);
        }
    }
    // dinv for the 4 output rows this lane writes
    float dv[4];
#pragma unroll
    for (int i = 0; i < 4; i++) {
        int r = row0 + (lane >> 4) * 4 + i;
        dv[i] = dinv[min(r, N - 1)];
    }

#pragma unroll
    for (int ct = 0; ct < 8; ct++) {
        f32x4 acc = {0.f, 0.f, 0.f, 0.f};
        int c = ct * 16 + lr;
#pragma unroll
        for (int ks = 0; ks < 4; ks++) {
            f16x8 bh = *(const f16x8*)&wth[(size_t)c * 128 + ks * 32 + lk];
            f16x8 bl = *(const f16x8*)&wtl[(size_t)c * 128 + ks * 32 + lk];
            acc = __builtin_amdgcn_mfma_f32_16x16x32_f16(ah[ks], bh, acc, 0, 0, 0);
            acc = __builtin_amdgcn_mfma_f32_16x16x32_f16(al[ks], bh, acc, 0, 0, 0);
            acc = __builtin_amdgcn_mfma_f32_16x16x32_f16(ah[ks], bl, acc, 0, 0, 0);
        }
#pragma unroll
        for (int i = 0; i < 4; i++) {
            int r = row0 + (lane >> 4) * 4 + i;
            if (r < N) {
                _Float16 hv = (_Float16)(dv[i] * acc[i]);
                out[(size_t)r * 128 + ct * 16 + lr] = *(__half*)&hv;
            }
        }
    }
}

// one wave per node (64-thread block: no intra-block degree tail); half2 per lane;
// fp32 accumulate; 8-deep MLP unroll.
__global__ __launch_bounds__(64) void k_agg128h(const __half* __restrict__ hs,
                                                const int* __restrict__ row_ptr,
                                                const unsigned short* __restrict__ ss,
                                                const float* __restrict__ dinv,
                                                const float* __restrict__ bias, int N,
                                                int do_relu, float* __restrict__ out) {
    int lane = threadIdx.x;
    int node = blockIdx.x;
    if (node >= N) return;
    const __half2* hp = (const __half2*)hs;  // row stride 64 half2
    float2 acc = __half22float2(hp[(size_t)node * 64 + lane]);  // self-loop term
    int s = row_ptr[node], e = row_ptr[node + 1];
    int i = s;
    for (; i + 8 <= e; i += 8) {
        int id[8];
#pragma unroll
        for (int u = 0; u < 8; u++) id[u] = __builtin_nontemporal_load(&ss[i + u]);
        float2 v[8];
#pragma unroll
        for (int u = 0; u < 8; u++) v[u] = __half22float2(hp[(size_t)id[u] * 64 + lane]);
        float sx0 = (v[0].x + v[1].x) + (v[2].x + v[3].x);
        float sx1 = (v[4].x + v[5].x) + (v[6].x + v[7].x);
        float sy0 = (v[0].y + v[1].y) + (v[2].y + v[3].y);
        float sy1 = (v[4].y + v[5].y) + (v[6].y + v[7].y);
        acc.x += sx0 + sx1;
        acc.y += sy0 + sy1;
    }
    for (; i < e; i++) {
        float2 v0 = __half22float2(hp[(size_t)ss[i] * 64 + lane]);
        acc.x += v0.x;
        acc.y += v0.y;
    }
    float di = dinv[node];
    int c = lane * 2;
    float2 b = *(const float2*)&bias[c];
    float ox = di * acc.x + b.x;
    float oy = di * acc.y + b.y;
    if (do_relu) {
        ox = fmaxf(ox, 0.f);
        oy = fmaxf(oy, 0.f);
    }
    *(float2*)&out[(size_t)node * 128 + c] = {ox, oy};
}

// heads: ths[n][j] = dinv[n] * sum_k h[n][k] * Wcat[k][j], Wcat = [W_age|W_sex|W_eth]
__global__ __launch_bounds__(256) void k_headgemm(const float* __restrict__ h,
                                                  const float* __restrict__ Wa,
                                                  const float* __restrict__ Wsx,
                                                  const float* __restrict__ We,
                                                  const float* __restrict__ dinv, int N,
                                                  float* __restrict__ ths) {
    __shared__ float Ws8[128][8];
    int tid = threadIdx.x;
#pragma unroll
    for (int j = 0; j < 4; j++) {
        int u = tid + j * 256;  // 1024 entries
        int k = u >> 3, c = u & 7;
        float v;
        if (c < 3) v = Wa[k * 3 + c];
        else if (c < 5) v = Wsx[k * 2 + (c - 3)];
        else v = We[k * 3 + (c - 5)];
        Ws8[k][c] = v;
    }
    __syncthreads();
    int node = blockIdx.x * 32 + (tid >> 3);
    int col = tid & 7;
    if (node >= N) return;
    const float* hr = &h[(size_t)node * 128];
    float acc = 0.f;
#pragma unroll 4
    for (int k = 0; k < 128; k += 4) {
        float4 hv = *(const float4*)&hr[k];
        acc += hv.x * Ws8[k][col] + hv.y * Ws8[k + 1][col] + hv.z * Ws8[k + 2][col] +
               hv.w * Ws8[k + 3][col];
    }
    ths[(size_t)node * 8 + col] = dinv[node] * acc;
}

__global__ __launch_bounds__(256) void k_agg8(const float* __restrict__ ths,
                                              const int* __restrict__ row_ptr,
                                              const unsigned short* __restrict__ ss,
                                              const float* __restrict__ dinv,
                                              const float* __restrict__ ba,
                                              const float* __restrict__ bs,
                                              const float* __restrict__ be, int N,
                                              float* __restrict__ outp) {
    int tid = threadIdx.x;
    int node = blockIdx.x * 32 + (tid >> 3);
    int j = tid & 7;
    if (node >= N) return;
    float acc = ths[(size_t)node * 8 + j];  // self
    int s = row_ptr[node], e = row_ptr[node + 1];
    for (int i = s; i < e; i++) {
        int sc = ss[i];
        acc += ths[(size_t)sc * 8 + j];
    }
    float bias = (j < 3) ? ba[j] : ((j < 5) ? bs[j - 3] : be[j - 5]);
    float v = dinv[node] * acc + bias;
    if (j < 3) outp[(size_t)node * 3 + j] = v;
    else if (j < 5) outp[(size_t)N * 3 + (size_t)node * 2 + (j - 3)] = v;
    else outp[(size_t)N * 5 + (size_t)node * 3 + (j - 5)] = v;
}

extern "C" void kernel_launch(void* const* d_in, const int* in_sizes, int n_in,
                              void* d_out, int out_size, void* d_ws, size_t ws_size,
                              hipStream_t stream) {
    const float* x = (const float*)d_in[0];
    const int* edge = (const int*)d_in[1];
    const float* W1 = (const float*)d_in[2];
    const float* b1 = (const float*)d_in[3];
    const float* W2 = (const float*)d_in[4];
    const float* b2 = (const float*)d_in[5];
    const float* Wa = (const float*)d_in[6];
    const float* ba = (const float*)d_in[7];
    const float* Wsx = (const float*)d_in[8];
    const float* bs = (const float*)d_in[9];
    const float* We = (const float*)d_in[10];
    const float* be = (const float*)d_in[11];

    int N = in_sizes[0] / 128;
    int E = in_sizes[1] / 2;
    const int* srcp = edge;
    const int* dstp = edge + E;
    int nbuk = (N + 127) >> 7;

    char* ws = (char*)d_ws;
    size_t off = 0;
    auto alloc = [&](size_t bytes) -> char* {
        char* p = ws + off;
        off += (bytes + 255) & ~(size_t)255;
        return p;
    };
    int* bcount = (int*)alloc((size_t)(nbuk + 1) * 4);
    int* bbase = (int*)alloc((size_t)(nbuk + 1) * 4);
    int* bcur = (int*)alloc((size_t)(nbuk + 1) * 4);
    int* row_ptr = (int*)alloc((size_t)(N + 1) * 4);
    float* dinv = (float*)alloc((size_t)N * 4);
    unsigned* bbuf = (unsigned*)alloc((size_t)E * 4);
    unsigned short* sorted = (unsigned short*)alloc((size_t)E * 2);
    __half* bufH = (__half*)alloc((size_t)N * 128 * 2);  // fp16 hs (gather operand)
    float* bufF = (float*)alloc((size_t)N * 128 * 4);    // fp32 agg output / gemm input
    float* ths = (float*)alloc((size_t)N * 8 * 4);
    __half* w1th = (__half*)alloc(128 * 128 * 2);
    __half* w1tl = (__half*)alloc(128 * 128 * 2);
    __half* w2th = (__half*)alloc(128 * 128 * 2);
    __half* w2tl = (__half*)alloc(128 * 128 * 2);

    int nbT = (E + EPB - 1) / EPB;

    hipMemsetAsync(bcount, 0, (size_t)(nbuk + 1) * 4, stream);
    k_bhist<<<nbT, 256, 0, stream>>>(dstp, E, nbuk, bcount);
    k_bscan<<<1, 512, 0, stream>>>(bcount, nbuk, bbase, bcur);
    k_passA<<<nbT, 256, 0, stream>>>(srcp, dstp, E, nbuk, bcur, bbuf);
    k_passB<<<nbuk, 256, 0, stream>>>(bbuf, bbase, N, row_ptr, dinv, sorted);
    k_wsplit<<<32, 64, 0, stream>>>(W1, w1th, w1tl);
    k_wsplit<<<32, 64, 0, stream>>>(W2, w2th, w2tl);

    int gb = (N + 63) / 64;
    k_gemm_mfma<<<gb, 256, 0, stream>>>(x, w1th, w1tl, dinv, N, bufH);
    k_agg128h<<<N, 64, 0, stream>>>(bufH, row_ptr, sorted, dinv, b1, N, 1, bufF);
    k_gemm_mfma<<<gb, 256, 0, stream>>>(bufF, w2th, w2tl, dinv, N, bufH);
    k_agg128h<<<N, 64, 0, stream>>>(bufH, row_ptr, sorted, dinv, b2, N, 1, bufF);
    k_headgemm<<<(N + 31) / 32, 256, 0, stream>>>(bufF, Wa, Wsx, We, dinv, N, ths);
    k_agg8<<<(N + 31) / 32, 256, 0, stream>>>(ths, row_ptr, sorted, dinv, ba, bs, be, N,
                                              (float*)d_out);
}

// Round 10
// 283.069 us; speedup vs baseline: 8.8136x; 1.0389x over previous
//
#include <hip/hip_runtime.h>
#include <hip/hip_fp16.h>

// GCN: out = dinv ⊙ ( A_sum ( dinv ⊙ (x@W) ) ) + b, A_sum includes self-loop.
// CSR (by dst) built on-device via bucketed multi-split (LDS atomics on hot path).
// Pull aggregation gathers a row-major fp16 copy of hs; fp32 accumulate.
// Layer-2 aggregation fuses the 3 head projections (128->8) into its epilogue:
// h2 (2 cols/lane) x LDS-staged WcatT[8][128], wave shfl_xor reduce, lane0 writes.

#define NBUK_MAX 512  // buckets of 128 nodes; N=50000 -> 391 buckets

__global__ __launch_bounds__(256) void k_bhist(const int* __restrict__ dst, int E, int nbuk,
                                               int* __restrict__ bcount) {
    __shared__ int h[NBUK_MAX];
    int tid = threadIdx.x;
    for (int i = tid; i < nbuk; i += 256) h[i] = 0;
    __syncthreads();
    int s0 = blockIdx.x * 4096;
#pragma unroll
    for (int i = 0; i < 16; i++) {
        int e = s0 + i * 256 + tid;
        if (e < E) atomicAdd(&h[dst[e] >> 7], 1);
    }
    __syncthreads();
    for (int i = tid; i < nbuk; i += 256)
        if (h[i]) atomicAdd(&bcount[i], h[i]);
}

__global__ __launch_bounds__(512) void k_bscan(const int* __restrict__ bcount, int nb,
                                               int* __restrict__ bbase, int* __restrict__ bcur) {
    __shared__ int s[512];
    int tid = threadIdx.x;
    int v = (tid < nb) ? bcount[tid] : 0;
    s[tid] = v;
    __syncthreads();
    for (int off = 1; off < 512; off <<= 1) {
        int t = (tid >= off) ? s[tid - off] : 0;
        __syncthreads();
        s[tid] += t;
        __syncthreads();
    }
    if (tid < nb) {
        int excl = s[tid] - v;
        bbase[tid] = excl;
        bcur[tid] = excl;
        if (tid == nb - 1) bbase[nb] = s[tid];
    }
}

__global__ __launch_bounds__(256) void k_passA(const int* __restrict__ src,
                                               const int* __restrict__ dst, int E, int nbuk,
                                               int* __restrict__ bcur,
                                               unsigned* __restrict__ bbuf) {
    __shared__ int h[NBUK_MAX];
    __shared__ int base[NBUK_MAX];
    __shared__ int lcur[NBUK_MAX];
    int tid = threadIdx.x;
    for (int i = tid; i < nbuk; i += 256) h[i] = 0;
    __syncthreads();
    int s0 = blockIdx.x * 4096;
#pragma unroll
    for (int i = 0; i < 16; i++) {
        int e = s0 + i * 256 + tid;
        if (e < E) atomicAdd(&h[dst[e] >> 7], 1);
    }
    __syncthreads();
    for (int i = tid; i < nbuk; i += 256) {
        int c = h[i];
        base[i] = c ? atomicAdd(&bcur[i], c) : 0;
        lcur[i] = 0;
    }
    __syncthreads();
#pragma unroll
    for (int i = 0; i < 16; i++) {
        int e = s0 + i * 256 + tid;
        if (e < E) {
            int d = dst[e];
            int b = d >> 7;
            int idx = atomicAdd(&lcur[b], 1);
            bbuf[base[b] + idx] = ((unsigned)d << 16) | (unsigned)src[e];
        }
    }
}

__global__ __launch_bounds__(256) void k_passB(const unsigned* __restrict__ bbuf,
                                               const int* __restrict__ bbase, int N,
                                               int* __restrict__ row_ptr,
                                               float* __restrict__ dinv,
                                               unsigned short* __restrict__ sorted) {
    __shared__ int h[128], sc[128], lc[128];
    int b = blockIdx.x, tid = threadIdx.x;
    int node0 = b << 7;
    int ncnt = min(128, N - node0);
    int s = bbase[b], e = bbase[b + 1];
    if (tid < 128) h[tid] = 0;
    __syncthreads();
    for (int i = s + tid; i < e; i += 256) atomicAdd(&h[(bbuf[i] >> 16) & 127], 1);
    __syncthreads();
    if (tid < 128) sc[tid] = h[tid];
    __syncthreads();
    for (int off = 1; off < 128; off <<= 1) {
        int t = 0;
        if (tid < 128 && tid >= off) t = sc[tid - off];
        __syncthreads();
        if (tid < 128) sc[tid] += t;
        __syncthreads();
    }
    if (tid < ncnt) {
        int excl = sc[tid] - h[tid];
        row_ptr[node0 + tid] = s + excl;
        dinv[node0 + tid] = rsqrtf((float)(h[tid] + 1));  // +1 self-loop
        lc[tid] = excl;
    }
    if (b == gridDim.x - 1 && tid == 0) row_ptr[N] = e;
    __syncthreads();
    for (int i = s + tid; i < e; i += 256) {
        unsigned p = bbuf[i];
        int nl = (p >> 16) & 127;
        int idx = atomicAdd(&lc[nl], 1);
        sorted[s + idx] = (unsigned short)(p & 0xffffu);
    }
}

// out[n][c] = (half) dinv[n] * sum_k in[n][k]*W[k][c]   (N x 128) @ (128 x 128)
__global__ __launch_bounds__(256) void k_gemm_scale_h(const float* __restrict__ in,
                                                      const float* __restrict__ W,
                                                      const float* __restrict__ dinv, int N,
                                                      __half* __restrict__ out) {
    __shared__ float Ws[32][128];
    __shared__ float Xs[32][64];
    int tid = threadIdx.x;
    int row0 = blockIdx.x * 64;
    int tc = tid & 15;   // 16 col groups x 8 cols
    int tr = tid >> 4;   // 16 row groups x 4 rows
    float acc[4][8];
#pragma unroll
    for (int i = 0; i < 4; i++)
#pragma unroll
        for (int j = 0; j < 8; j++) acc[i][j] = 0.f;

    for (int k0 = 0; k0 < 128; k0 += 32) {
#pragma unroll
        for (int j = 0; j < 4; j++) {  // stage W chunk: 32x128 = 1024 float4
            int u = tid + j * 256;
            int kk = u >> 5, c4 = u & 31;
            *(float4*)&Ws[kk][c4 * 4] = *(const float4*)&W[(k0 + kk) * 128 + c4 * 4];
        }
#pragma unroll
        for (int j = 0; j < 2; j++) {  // stage X chunk transposed: 64 rows x 32 k
            int u = tid + j * 256;     // 512 float4 units
            int r = u >> 3, kq = u & 7;
            int row = row0 + r;
            if (row > N - 1) row = N - 1;
            float4 v = *(const float4*)&in[(size_t)row * 128 + k0 + kq * 4];
            Xs[kq * 4 + 0][r] = v.x;
            Xs[kq * 4 + 1][r] = v.y;
            Xs[kq * 4 + 2][r] = v.z;
            Xs[kq * 4 + 3][r] = v.w;
        }
        __syncthreads();
#pragma unroll 8
        for (int kk = 0; kk < 32; kk++) {
            float4 xv = *(const float4*)&Xs[kk][tr * 4];
            float4 wa = *(const float4*)&Ws[kk][tc * 8];
            float4 wb = *(const float4*)&Ws[kk][tc * 8 + 4];
            float xr[4] = {xv.x, xv.y, xv.z, xv.w};
            float wc[8] = {wa.x, wa.y, wa.z, wa.w, wb.x, wb.y, wb.z, wb.w};
#pragma unroll
            for (int i = 0; i < 4; i++)
#pragma unroll
                for (int j = 0; j < 8; j++) acc[i][j] += xr[i] * wc[j];
        }
        __syncthreads();
    }
#pragma unroll
    for (int i = 0; i < 4; i++) {
        int row = row0 + tr * 4 + i;
        if (row < N) {
            float di = dinv[row];
            union {
                uint4 u;
                __half h[8];
            } pk;
#pragma unroll
            for (int j = 0; j < 8; j++) pk.h[j] = __float2half_rn(di * acc[i][j]);
            *(uint4*)&out[(size_t)row * 128 + tc * 8] = pk.u;
        }
    }
}

// layer-1 agg: one wave per node (4/block); half2 per lane; fp32 accumulate.
__global__ __launch_bounds__(256) void k_agg128h(const __half* __restrict__ hs,
                                                 const int* __restrict__ row_ptr,
                                                 const unsigned short* __restrict__ ss,
                                                 const float* __restrict__ dinv,
                                                 const float* __restrict__ bias, int N,
                                                 float* __restrict__ out) {
    int wid = threadIdx.x >> 6;
    int lane = threadIdx.x & 63;
    int node = blockIdx.x * 4 + wid;
    if (node >= N) return;
    const __half2* hp = (const __half2*)hs;  // row stride 64 half2
    float2 acc = __half22float2(hp[(size_t)node * 64 + lane]);  // self-loop term
    int s = row_ptr[node], e = row_ptr[node + 1];
    int i = s;
    for (; i + 4 <= e; i += 4) {
        int s0 = ss[i], s1 = ss[i + 1], s2 = ss[i + 2], s3 = ss[i + 3];
        float2 v0 = __half22float2(hp[(size_t)s0 * 64 + lane]);
        float2 v1 = __half22float2(hp[(size_t)s1 * 64 + lane]);
        float2 v2 = __half22float2(hp[(size_t)s2 * 64 + lane]);
        float2 v3 = __half22float2(hp[(size_t)s3 * 64 + lane]);
        acc.x += (v0.x + v1.x) + (v2.x + v3.x);
        acc.y += (v0.y + v1.y) + (v2.y + v3.y);
    }
    for (; i < e; i++) {
        float2 v0 = __half22float2(hp[(size_t)ss[i] * 64 + lane]);
        acc.x += v0.x;
        acc.y += v0.y;
    }
    float di = dinv[node];
    int c = lane * 2;
    float2 b = *(const float2*)&bias[c];
    float ox = fmaxf(di * acc.x + b.x, 0.f);
    float oy = fmaxf(di * acc.y + b.y, 0.f);
    *(float2*)&out[(size_t)node * 128 + c] = {ox, oy};
}

// layer-2 agg fused with head projection: epilogue computes h2 = relu(dinv*acc+b2)
// (2 cols/lane), then ths[n][j] = dinv[n] * sum_c h2[c]*Wcat[c][j] via LDS-staged
// WcatT[8][128] + wave shfl_xor reduction. Writes only ths (N x 8 fp32).
__global__ __launch_bounds__(256) void k_agg128hf(const __half* __restrict__ hs,
                                                  const int* __restrict__ row_ptr,
                                                  const unsigned short* __restrict__ ss,
                                                  const float* __restrict__ dinv,
                                                  const float* __restrict__ bias,
                                                  const float* __restrict__ Wa,
                                                  const float* __restrict__ Wsx,
                                                  const float* __restrict__ We, int N,
                                                  float* __restrict__ ths) {
    __shared__ float WcT[8][128];  // WcT[j][k] = Wcat[k][j]
    int tid = threadIdx.x;
#pragma unroll
    for (int q = 0; q < 4; q++) {
        int u = tid + q * 256;  // 1024 entries
        int k = u >> 3, j = u & 7;
        float v;
        if (j < 3) v = Wa[k * 3 + j];
        else if (j < 5) v = Wsx[k * 2 + (j - 3)];
        else v = We[k * 3 + (j - 5)];
        WcT[j][k] = v;
    }
    __syncthreads();

    int wid = tid >> 6;
    int lane = tid & 63;
    int node = blockIdx.x * 4 + wid;
    if (node >= N) return;
    const __half2* hp = (const __half2*)hs;  // row stride 64 half2
    float2 acc = __half22float2(hp[(size_t)node * 64 + lane]);  // self-loop term
    int s = row_ptr[node], e = row_ptr[node + 1];
    int i = s;
    for (; i + 4 <= e; i += 4) {
        int s0 = ss[i], s1 = ss[i + 1], s2 = ss[i + 2], s3 = ss[i + 3];
        float2 v0 = __half22float2(hp[(size_t)s0 * 64 + lane]);
        float2 v1 = __half22float2(hp[(size_t)s1 * 64 + lane]);
        float2 v2 = __half22float2(hp[(size_t)s2 * 64 + lane]);
        float2 v3 = __half22float2(hp[(size_t)s3 * 64 + lane]);
        acc.x += (v0.x + v1.x) + (v2.x + v3.x);
        acc.y += (v0.y + v1.y) + (v2.y + v3.y);
    }
    for (; i < e; i++) {
        float2 v0 = __half22float2(hp[(size_t)ss[i] * 64 + lane]);
        acc.x += v0.x;
        acc.y += v0.y;
    }
    float di = dinv[node];
    int c = lane * 2;
    float2 b = *(const float2*)&bias[c];
    float ox = fmaxf(di * acc.x + b.x, 0.f);  // h2[c]
    float oy = fmaxf(di * acc.y + b.y, 0.f);  // h2[c+1]

    float p[8];
#pragma unroll
    for (int j = 0; j < 8; j++) {
        float2 w = *(const float2*)&WcT[j][c];
        p[j] = ox * w.x + oy * w.y;
    }
#pragma unroll
    for (int m = 1; m < 64; m <<= 1) {
#pragma unroll
        for (int j = 0; j < 8; j++) p[j] += __shfl_xor(p[j], m);
    }
    if (lane == 0) {
#pragma unroll
        for (int j = 0; j < 8; j++) ths[(size_t)node * 8 + j] = di * p[j];
    }
}

__global__ __launch_bounds__(256) void k_agg8(const float* __restrict__ ths,
                                              const int* __restrict__ row_ptr,
                                              const unsigned short* __restrict__ ss,
                                              const float* __restrict__ dinv,
                                              const float* __restrict__ ba,
                                              const float* __restrict__ bs,
                                              const float* __restrict__ be, int N,
                                              float* __restrict__ outp) {
    int tid = threadIdx.x;
    int node = blockIdx.x * 32 + (tid >> 3);
    int j = tid & 7;
    if (node >= N) return;
    float acc = ths[(size_t)node * 8 + j];  // self
    int s = row_ptr[node], e = row_ptr[node + 1];
    for (int i = s; i < e; i++) {
        int sc = ss[i];
        acc += ths[(size_t)sc * 8 + j];
    }
    float bias = (j < 3) ? ba[j] : ((j < 5) ? bs[j - 3] : be[j - 5]);
    float v = dinv[node] * acc + bias;
    if (j < 3) outp[(size_t)node * 3 + j] = v;
    else if (j < 5) outp[(size_t)N * 3 + (size_t)node * 2 + (j - 3)] = v;
    else outp[(size_t)N * 5 + (size_t)node * 3 + (j - 5)] = v;
}

extern "C" void kernel_launch(void* const* d_in, const int* in_sizes, int n_in,
                              void* d_out, int out_size, void* d_ws, size_t ws_size,
                              hipStream_t stream) {
    const float* x = (const float*)d_in[0];
    const int* edge = (const int*)d_in[1];
    const float* W1 = (const float*)d_in[2];
    const float* b1 = (const float*)d_in[3];
    const float* W2 = (const float*)d_in[4];
    const float* b2 = (const float*)d_in[5];
    const float* Wa = (const float*)d_in[6];
    const float* ba = (const float*)d_in[7];
    const float* Wsx = (const float*)d_in[8];
    const float* bs = (const float*)d_in[9];
    const float* We = (const float*)d_in[10];
    const float* be = (const float*)d_in[11];

    int N = in_sizes[0] / 128;
    int E = in_sizes[1] / 2;
    const int* srcp = edge;
    const int* dstp = edge + E;
    int nbuk = (N + 127) >> 7;

    char* ws = (char*)d_ws;
    size_t off = 0;
    auto alloc = [&](size_t bytes) -> char* {
        char* p = ws + off;
        off += (bytes + 255) & ~(size_t)255;
        return p;
    };
    int* bcount = (int*)alloc((size_t)(nbuk + 1) * 4);
    int* bbase = (int*)alloc((size_t)(nbuk + 1) * 4);
    int* bcur = (int*)alloc((size_t)(nbuk + 1) * 4);
    int* row_ptr = (int*)alloc((size_t)(N + 1) * 4);
    float* dinv = (float*)alloc((size_t)N * 4);
    unsigned* bbuf = (unsigned*)alloc((size_t)E * 4);
    unsigned short* sorted = (unsigned short*)alloc((size_t)E * 2);
    __half* bufH = (__half*)alloc((size_t)N * 128 * 2);  // fp16 hs (gather operand)
    float* bufF = (float*)alloc((size_t)N * 128 * 4);    // fp32 layer-1 agg output
    float* ths = (float*)alloc((size_t)N * 8 * 4);

    int nbT = (E + 4095) / 4096;

    hipMemsetAsync(bcount, 0, (size_t)(nbuk + 1) * 4, stream);
    k_bhist<<<nbT, 256, 0, stream>>>(dstp, E, nbuk, bcount);
    k_bscan<<<1, 512, 0, stream>>>(bcount, nbuk, bbase, bcur);
    k_passA<<<nbT, 256, 0, stream>>>(srcp, dstp, E, nbuk, bcur, bbuf);
    k_passB<<<nbuk, 256, 0, stream>>>(bbuf, bbase, N, row_ptr, dinv, sorted);

    int gb = (N + 63) / 64;
    int ab = (N + 3) / 4;
    k_gemm_scale_h<<<gb, 256, 0, stream>>>(x, W1, dinv, N, bufH);
    k_agg128h<<<ab, 256, 0, stream>>>(bufH, row_ptr, sorted, dinv, b1, N, bufF);
    k_gemm_scale_h<<<gb, 256, 0, stream>>>(bufF, W2, dinv, N, bufH);
    k_agg128hf<<<ab, 256, 0, stream>>>(bufH, row_ptr, sorted, dinv, b2, Wa, Wsx, We, N,
                                       ths);
    k_agg8<<<(N + 31) / 32, 256, 0, stream>>>(ths, row_ptr, sorted, dinv, ba, bs, be, N,
                                              (float*)d_out);
}